// Round 2
// baseline (690.729 us; speedup 1.0000x reference)
//
#include <hip/hip_runtime.h>
#include <math.h>

// EfficientDet postprocess for MI355X — round 1.
// anchors+zero -> decode -> fixed-edge candidate scan (reads logits ONCE,
// coalesced) -> per-(b,c) sort+NMS over <=1024 candidates -> exact fallback
// (rare/never) -> per-batch frontier-merge top-100.

#define NANCH 49104
#define NB 8
#define NC 90
#define NBC 720
#define POSTN 100
#define T1CAP 1024
#define EDGE 0.91f      // P(sigmoid(N(0,1)) >= 0.91) ~ 1.04% -> ~509 +/- 22 cands
#define PRECHK 2.0f     // sigmoid(2.0)=0.8808 < EDGE: safe cheap pre-filter

// ---------- exact-float helpers (mirror numpy f32 semantics, no FMA) ----------

__device__ __forceinline__ float sigmoid_ref(float x) {
  if (x >= 0.0f) return __fdiv_rn(1.0f, __fadd_rn(1.0f, expf(-x)));
  float e = expf(x);
  return __fdiv_rn(e, __fadd_rn(1.0f, e));
}

__device__ __forceinline__ float iou_ref(float4 a, float4 b) {
  float yy1 = fmaxf(a.x, b.x);
  float xx1 = fmaxf(a.y, b.y);
  float yy2 = fminf(a.z, b.z);
  float xx2 = fminf(a.w, b.w);
  float ih = fmaxf(__fsub_rn(yy2, yy1), 0.0f);
  float iw = fmaxf(__fsub_rn(xx2, xx1), 0.0f);
  float inter = __fmul_rn(ih, iw);
  float a1 = __fmul_rn(__fsub_rn(a.z, a.x), __fsub_rn(a.w, a.y));
  float a2 = __fmul_rn(__fsub_rn(b.z, b.x), __fsub_rn(b.w, b.y));
  float den = __fadd_rn(__fsub_rn(__fadd_rn(a1, a2), inter), 1e-8f);
  return __fdiv_rn(inter, den);
}

// ---------------------------- anchors (+ counter zeroing) ----------------------

__global__ __launch_bounds__(256) void k_anchors(float4* __restrict__ anchors,
                                                 unsigned int* __restrict__ gcnt) {
  int n = blockIdx.x * 256 + threadIdx.x;
  if (n < NBC) gcnt[n] = 0u;
  if (n >= NANCH) return;
  int l, off;
  if (n < 36864)      { l = 0; off = 0; }
  else if (n < 46080) { l = 1; off = 36864; }
  else if (n < 48384) { l = 2; off = 46080; }
  else if (n < 48960) { l = 3; off = 48384; }
  else                { l = 4; off = 48960; }
  int stride = 8 << l;
  int feat = 64 >> l;
  int r = n - off;
  int cell = r / 9, a = r - cell * 9;
  int iy = cell / feat, ix = cell - iy * feat;
  int isc = a / 3, ir = a - isc * 3;
  // numpy computes half-sizes in float64, then casts to float32
  double base = exp2((double)isc / 3.0) * (double)stride * 4.0;
  double rt = (ir == 0) ? 1.0 : (ir == 1 ? 0.5 : 2.0);
  double sq = sqrt(rt);
  float hh = (float)(base / sq / 2.0);
  float hw = (float)(base * sq / 2.0);
  float cy = __fmul_rn(__fadd_rn((float)iy, 0.5f), (float)stride);
  float cx = __fmul_rn(__fadd_rn((float)ix, 0.5f), (float)stride);
  anchors[n] = make_float4(__fsub_rn(cy, hh), __fsub_rn(cx, hw),
                           __fadd_rn(cy, hh), __fadd_rn(cx, hw));
}

// ---------------------------- decode -------------------------------------------

__global__ __launch_bounds__(256) void k_decode(const float4* __restrict__ deltas,
                                                const float4* __restrict__ anchors,
                                                float4* __restrict__ boxes) {
  int i = blockIdx.x * 256 + threadIdx.x;
  if (i >= NB * NANCH) return;
  int n = i % NANCH;
  float4 a = anchors[n];
  float4 d = deltas[i];
  float ah = __fsub_rn(a.z, a.x);
  float aw = __fsub_rn(a.w, a.y);
  float acy = __fmul_rn(__fadd_rn(a.x, a.z), 0.5f);
  float acx = __fmul_rn(__fadd_rn(a.y, a.w), 0.5f);
  float cy = __fadd_rn(__fmul_rn(d.x, ah), acy);
  float cx = __fadd_rn(__fmul_rn(d.y, aw), acx);
  float h = __fmul_rn(expf(d.z), ah);
  float w = __fmul_rn(expf(d.w), aw);
  float y1 = __fsub_rn(cy, __fmul_rn(h, 0.5f));
  float x1 = __fsub_rn(cx, __fmul_rn(w, 0.5f));
  float y2 = __fadd_rn(cy, __fmul_rn(h, 0.5f));
  float x2 = __fadd_rn(cx, __fmul_rn(w, 0.5f));
  const float inv = 0.001953125f;  // 1/512, exact
  y1 = fminf(fmaxf(__fmul_rn(y1, inv), 0.0f), 1.0f);
  x1 = fminf(fmaxf(__fmul_rn(x1, inv), 0.0f), 1.0f);
  y2 = fminf(fmaxf(__fmul_rn(y2, inv), 0.0f), 1.0f);
  x2 = fminf(fmaxf(__fmul_rn(x2, inv), 0.0f), 1.0f);
  boxes[i] = make_float4(y1, x1, y2, x2);
}

// -------------------- fixed-edge candidate scan (single logits pass) -----------
// grid: (768, 8). Each block: 64 anchors x 90 classes = 1440 float4, coalesced.
// Candidates (score>=EDGE) appended to per-(b,c) global list as packed u64:
// (score_bits<<32)|(65535-n)  -> descending u64 order == (score desc, n asc).

__global__ __launch_bounds__(256) void k_scan(const float4* __restrict__ logits4,
                                              unsigned long long* __restrict__ gcand,
                                              unsigned int* __restrict__ gcnt) {
  int b = blockIdx.y;
  int n0 = blockIdx.x * 64;
  int rows = min(64, NANCH - n0);
  const float4* base = logits4 + ((size_t)b * NANCH + n0) * 90 / 4;
  int tot4 = rows * 90 / 4;
  for (int e4 = threadIdx.x; e4 < tot4; e4 += 256) {
    float4 v = base[e4];
    float xs[4] = {v.x, v.y, v.z, v.w};
#pragma unroll
    for (int j = 0; j < 4; j++) {
      float x = xs[j];
      if (x >= PRECHK) {  // cheap pre-filter: skips sigmoid for ~98% of elems
        float s = sigmoid_ref(x);
        if (s >= EDGE) {
          int e = e4 * 4 + j;
          int r = e / 90, c = e - r * 90;
          int bc = b * 90 + c;
          unsigned int pos = atomicAdd(&gcnt[bc], 1u);
          if (pos < T1CAP) {
            unsigned long long pk =
                ((unsigned long long)__float_as_uint(s) << 32) |
                (unsigned int)(65535 - (n0 + r));
            gcand[(size_t)bc * T1CAP + pos] = pk;
          }
        }
      }
    }
  }
}

// -------------------- tier1: sort <=1024 candidates + greedy NMS ----------------

__global__ __launch_bounds__(256) void k_nms_t1(
    const unsigned long long* __restrict__ gcand,
    const unsigned int* __restrict__ gcnt, const float4* __restrict__ boxes,
    float* __restrict__ sel_s, float4* __restrict__ sel_b,
    int* __restrict__ flags) {
  int bc = blockIdx.x;
  int b = bc / NC;
  int tid = threadIdx.x;

  __shared__ unsigned long long cand[T1CAP];
  __shared__ float4 cbox[T1CAP];
  __shared__ unsigned char alive[T1CAP];
  __shared__ float4 s_selbox[POSTN];
  __shared__ float s_sels[POSTN];
  __shared__ int s_nsel;

  unsigned int cnt = gcnt[bc];
  bool overflow = (cnt > (unsigned)T1CAP);
  int M = (int)min(cnt, (unsigned)T1CAP);
  for (int e = tid; e < T1CAP; e += 256)
    cand[e] = (e < M) ? gcand[(size_t)bc * T1CAP + e] : 0ull;
  if (tid == 0) s_nsel = 0;
  __syncthreads();

  // bitonic sort descending (key = score desc, tie idx asc via 65535-n packing)
  for (int k = 2; k <= T1CAP; k <<= 1) {
    for (int j = k >> 1; j > 0; j >>= 1) {
      for (int t = tid; t < T1CAP / 2; t += 256) {
        int i = ((t & ~(j - 1)) << 1) | (t & (j - 1));
        int p = i | j;
        unsigned long long a = cand[i], bb = cand[p];
        bool up = ((i & k) == 0);
        if (up ? (a < bb) : (a > bb)) { cand[i] = bb; cand[p] = a; }
      }
      __syncthreads();
    }
  }

  for (int e = tid; e < M; e += 256) {
    int n = 65535 - (int)(cand[e] & 0xFFFFull);
    cbox[e] = boxes[(size_t)b * NANCH + n];
    alive[e] = 1;
  }
  __syncthreads();

  // serial greedy NMS (exact reference order: score desc, anchor idx asc)
  for (int i = 0; i < M; i++) {
    if (s_nsel >= POSTN) break;  // uniform (barriered)
    if (!alive[i]) continue;     // uniform
    float4 bi = cbox[i];
    float sc = __uint_as_float((unsigned int)(cand[i] >> 32));
    if (!(iou_ref(bi, bi) > 0.5f)) {
      // degenerate zero-area box: never self-suppresses -> reference re-selects
      // it for every remaining step ("sticky" fill)
      if (tid == 0) {
        for (int p = s_nsel; p < POSTN; p++) { s_selbox[p] = bi; s_sels[p] = sc; }
        s_nsel = POSTN;
      }
      __syncthreads();
      break;
    }
    for (int t = i + 1 + tid; t < M; t += 256)
      if (alive[t] && iou_ref(cbox[t], bi) > 0.5f) alive[t] = 0;
    if (tid == 0) {
      s_selbox[s_nsel] = bi;
      s_sels[s_nsel] = sc;
      s_nsel = s_nsel + 1;
    }
    __syncthreads();
  }
  __syncthreads();
  int ns = s_nsel;

  // valid only if 100 selections completed from a complete (non-overflowed) list
  bool bad = overflow || (ns < POSTN);
  if (tid == 0) flags[bc] = bad ? 1 : 0;
  if (bad) return;
  for (int p = tid; p < POSTN; p += 256) {
    float s0 = s_sels[p];
    bool valid = (s0 > 0.2f);  // SCORE_THR gate (always true here: s0>=EDGE)
    sel_s[bc * POSTN + p] = valid ? s0 : 0.0f;
    sel_b[bc * POSTN + p] = valid ? s_selbox[p] : make_float4(0, 0, 0, 0);
  }
}

// -------- exact fallback: histogram rank-5000 + sort + NMS (rare/never) --------

template <int CAP, int RANK>
__global__ __launch_bounds__(256) void k_nms_fb(const float* __restrict__ logits,
                                                const float4* __restrict__ boxes,
                                                float* __restrict__ sel_s,
                                                float4* __restrict__ sel_b,
                                                const int* __restrict__ flags) {
  int bc = blockIdx.x;
  if (flags[bc] == 0) return;
  int b = bc / NC;
  int c = bc - b * NC;
  int tid = threadIdx.x;

  __shared__ unsigned int s_key[CAP];
  __shared__ unsigned short s_idx[CAP];
  __shared__ __align__(16) unsigned char s_pool[8192];
  __shared__ unsigned int s_bsum[256];
  __shared__ unsigned char s_alive[512];
  __shared__ float4 s_selbox[POSTN];
  __shared__ float s_sels[POSTN];
  __shared__ int s_cnt, s_nsel, s_cutbin;

  const float* lrow = logits + (size_t)b * NANCH * 90 + c;

  unsigned int* hist = (unsigned int*)s_pool;
  for (int e = tid; e < 2048; e += 256) hist[e] = 0u;
  if (tid == 0) { s_cnt = 0; s_nsel = 0; s_cutbin = 0; }
  __syncthreads();

  for (int n = tid; n < NANCH; n += 256) {
    float s = sigmoid_ref(lrow[(size_t)n * 90]);
    int bin = (int)(s * 2048.0f);
    if (bin > 2047) bin = 2047;
    atomicAdd(&hist[bin], 1u);
  }
  __syncthreads();
  unsigned int loc = 0;
#pragma unroll
  for (int k = 0; k < 8; k++) loc += hist[tid * 8 + k];
  s_bsum[tid] = loc;
  __syncthreads();
  if (tid == 0) {
    unsigned int cum = 0;
    int bin = 0;
    bool fnd = false;
    for (int t = 255; t >= 0 && !fnd; t--) {
      if (cum + s_bsum[t] >= (unsigned)RANK) {
        for (int kk = 7; kk >= 0; kk--) {
          unsigned int h = hist[t * 8 + kk];
          if (cum + h >= (unsigned)RANK) { bin = t * 8 + kk; fnd = true; break; }
          cum += h;
        }
      } else {
        cum += s_bsum[t];
      }
    }
    s_cutbin = bin;
  }
  __syncthreads();
  float edge = __fmul_rn((float)s_cutbin, (1.0f / 2048.0f));  // exact

  for (int n = tid; n < NANCH; n += 256) {
    float s = sigmoid_ref(lrow[(size_t)n * 90]);
    if (s >= edge) {
      int pos = atomicAdd(&s_cnt, 1);
      if (pos < CAP) {
        s_key[pos] = __float_as_uint(s);
        s_idx[pos] = (unsigned short)n;
      }
    }
  }
  __syncthreads();
  int M = s_cnt;
  if (M > CAP) M = CAP;
  for (int e = M + tid; e < CAP; e += 256) { s_key[e] = 0u; s_idx[e] = 0xFFFFu; }
  __syncthreads();

  for (int k = 2; k <= CAP; k <<= 1) {
    for (int j = k >> 1; j > 0; j >>= 1) {
      for (int t = tid; t < CAP / 2; t += 256) {
        int i = ((t & ~(j - 1)) << 1) | (t & (j - 1));
        int p = i | j;
        unsigned int ka = s_key[i], kb = s_key[p];
        unsigned short ia = s_idx[i], ib = s_idx[p];
        bool up = ((i & k) == 0);
        bool g = (ka < kb) || (ka == kb && ia > ib);
        bool l = (kb < ka) || (ka == kb && ib > ia);
        if (up ? g : l) {
          s_key[i] = kb; s_key[p] = ka;
          s_idx[i] = ib; s_idx[p] = ia;
        }
      }
      __syncthreads();
    }
  }

  float4* cbox = (float4*)s_pool;
  int L = (M < 5000) ? M : 5000;  // PRE_NMS truncation (stable)
  for (int base = 0; base < L; base += 512) {
    int cn = min(512, L - base);
    int ns0 = s_nsel;
    if (ns0 >= POSTN) break;
    for (int t = tid; t < cn; t += 256) {
      int n = s_idx[base + t];
      float4 bx = boxes[(size_t)b * NANCH + n];
      bool al = true;
      for (int s = 0; s < ns0; s++) {
        if (iou_ref(bx, s_selbox[s]) > 0.5f) { al = false; break; }
      }
      cbox[t] = bx;
      s_alive[t] = al ? 1 : 0;
    }
    __syncthreads();
    for (int i = 0; i < cn; i++) {
      if (s_nsel >= POSTN) break;
      if (!s_alive[i]) continue;
      float4 bi = cbox[i];
      float sc = __uint_as_float(s_key[base + i]);
      if (!(iou_ref(bi, bi) > 0.5f)) {
        if (tid == 0) {
          for (int p = s_nsel; p < POSTN; p++) { s_selbox[p] = bi; s_sels[p] = sc; }
          s_nsel = POSTN;
        }
        __syncthreads();
        break;
      }
      for (int t = tid; t < cn; t += 256) {
        if (t > i && s_alive[t] && iou_ref(cbox[t], bi) > 0.5f) s_alive[t] = 0;
      }
      if (tid == 0) {
        s_selbox[s_nsel] = bi;
        s_sels[s_nsel] = sc;
        s_nsel = s_nsel + 1;
      }
      __syncthreads();
    }
    __syncthreads();
    if (s_nsel >= POSTN) break;
  }
  __syncthreads();
  int ns = s_nsel;
  for (int p = tid; p < POSTN; p += 256) {
    float sc = 0.0f;
    float4 bx = make_float4(0.0f, 0.0f, 0.0f, 0.0f);
    if (p < ns) {
      float s0 = s_sels[p];
      if (s0 > 0.2f) { sc = s0; bx = s_selbox[p]; }
    }
    sel_s[bc * POSTN + p] = sc;
    sel_b[bc * POSTN + p] = bx;
  }
}

// ---------------- per-batch top-100: frontier merge of 90 sorted lists ----------
// Per-class sel_s rows are non-increasing (greedy NMS emits descending; zero
// tail). Global stable top-100 == 100 steps of stable 90-way frontier max.

__global__ __launch_bounds__(256) void k_final(const float* __restrict__ sel_s,
                                               const float4* __restrict__ sel_b,
                                               float* __restrict__ out) {
  int b = blockIdx.x;
  int tid = threadIdx.x;
  __shared__ float key[9000];
  __shared__ int ptr[NC];
  __shared__ unsigned long long wred[4];
  __shared__ unsigned int win_k[POSTN];
  __shared__ int win_e[POSTN];
  for (int e = tid; e < 9000; e += 256) key[e] = sel_s[(size_t)b * 9000 + e];
  if (tid < NC) ptr[tid] = 0;
  __syncthreads();
  int lane = tid & 63, wid = tid >> 6;
  for (int p = 0; p < POSTN; p++) {
    unsigned long long v = 0ull;
    if (tid < NC) {
      int pp = ptr[tid];
      if (pp < POSTN) {
        int e = tid * POSTN + pp;
        v = ((unsigned long long)__float_as_uint(key[e]) << 32) |
            (unsigned int)(16383 - e);  // max score, then min flat idx (stable)
      }
    }
    for (int d = 32; d > 0; d >>= 1) {
      unsigned long long o = __shfl_down(v, (unsigned)d, 64);
      if (o > v) v = o;
    }
    if (lane == 0) wred[wid] = v;
    __syncthreads();
    if (tid == 0) {
      unsigned long long w = wred[0];
      if (wred[1] > w) w = wred[1];
      int e = 16383 - (int)(w & 0x3FFFull);
      win_k[p] = (unsigned int)(w >> 32);
      win_e[p] = e;
      ptr[e / POSTN] = (e % POSTN) + 1;
    }
    __syncthreads();
  }
  if (tid < POSTN) {
    int p = tid;
    unsigned int k = win_k[p];
    int e = win_e[p];
    float4 bx = sel_b[(size_t)b * 9000 + e];
    ((float4*)out)[b * POSTN + p] = bx;              // out_b [8,100,4]
    out[3200 + b * POSTN + p] = __uint_as_float(k);  // out_s [8,100]
    out[4000 + b * POSTN + p] = (float)(e / POSTN);  // out_c [8,100]
  }
  if (tid == 0) {
    int v = 0;
    for (int p = 0; p < POSTN; p++) v += (win_k[p] != 0u) ? 1 : 0;
    out[4800 + b] = (float)v;  // valid [8]
  }
}

// ------------------------------- launcher --------------------------------------

extern "C" void kernel_launch(void* const* d_in, const int* in_sizes, int n_in,
                              void* d_out, int out_size, void* d_ws, size_t ws_size,
                              hipStream_t stream) {
  const float* deltas = (const float*)d_in[0];  // [8,49104,4]
  const float* logits = (const float*)d_in[1];  // [8,49104,90]
  float* out = (float*)d_out;
  char* ws = (char*)d_ws;

  size_t off = 0;
  auto take = [&](size_t bytes) -> char* {
    char* p = ws + off;
    off += (bytes + 255) & ~(size_t)255;
    return p;
  };
  float4* anchors = (float4*)take((size_t)NANCH * 16);
  float4* boxes = (float4*)take((size_t)NB * NANCH * 16);
  float* sel_s = (float*)take((size_t)NBC * POSTN * 4);
  float4* sel_b = (float4*)take((size_t)NBC * POSTN * 16);
  int* flags = (int*)take((size_t)NBC * 4);
  unsigned int* gcnt = (unsigned int*)take((size_t)NBC * 4);
  unsigned long long* gcand =
      (unsigned long long*)take((size_t)NBC * T1CAP * 8);

  k_anchors<<<dim3((NANCH + 255) / 256), dim3(256), 0, stream>>>(anchors, gcnt);
  k_decode<<<dim3((NB * NANCH + 255) / 256), dim3(256), 0, stream>>>(
      (const float4*)deltas, anchors, boxes);
  k_scan<<<dim3((NANCH + 63) / 64, NB), dim3(256), 0, stream>>>(
      (const float4*)logits, gcand, gcnt);
  k_nms_t1<<<dim3(NBC), dim3(256), 0, stream>>>(gcand, gcnt, boxes, sel_s,
                                                sel_b, flags);
  k_nms_fb<8192, 5000><<<dim3(NBC), dim3(256), 0, stream>>>(logits, boxes,
                                                            sel_s, sel_b, flags);
  k_final<<<dim3(NB), dim3(256), 0, stream>>>(sel_s, sel_b, out);
}

// Round 4
// 387.370 us; speedup vs baseline: 1.7831x; 1.7831x over previous
//
#include <hip/hip_runtime.h>
#include <math.h>

// EfficientDet postprocess for MI355X — round 4.
// WS-overflow fix: R3 failed because gcand cells needed 26.5 MB (> ws). This
// round keeps R2's PROVEN 14.4 MB layout + t1/final/fb verbatim, and fixes the
// R2 k_scan bottleneck (global atomics) via LDS aggregation + one reservation
// atomicAdd per (class,chunk) (69K atomics vs 366K, ~5 slots each).

#define NANCH 49104
#define NB 8
#define NC 90
#define NBC 720
#define POSTN 100
#define T1CAP 1024
#define CHUNK 512
#define NCH 96          // ceil(49104/512)
#define LCAP 32         // per-(class,chunk) LDS list cap; Poisson(5.3) -> ~11 sigma
#define EDGE 0.91f      // P(sigmoid(N(0,1)) >= 0.91) ~ 1.04% -> ~509 +/- 22 per (b,c)
#define PRECHK 2.0f     // sigmoid(2.0)=0.8808 < EDGE: safe cheap pre-filter

// ---------- exact-float helpers (mirror numpy f32 semantics, no FMA) ----------

__device__ __forceinline__ float sigmoid_ref(float x) {
  if (x >= 0.0f) return __fdiv_rn(1.0f, __fadd_rn(1.0f, expf(-x)));
  float e = expf(x);
  return __fdiv_rn(e, __fadd_rn(1.0f, e));
}

__device__ __forceinline__ float iou_ref(float4 a, float4 b) {
  float yy1 = fmaxf(a.x, b.x);
  float xx1 = fmaxf(a.y, b.y);
  float yy2 = fminf(a.z, b.z);
  float xx2 = fminf(a.w, b.w);
  float ih = fmaxf(__fsub_rn(yy2, yy1), 0.0f);
  float iw = fmaxf(__fsub_rn(xx2, xx1), 0.0f);
  float inter = __fmul_rn(ih, iw);
  float a1 = __fmul_rn(__fsub_rn(a.z, a.x), __fsub_rn(a.w, a.y));
  float a2 = __fmul_rn(__fsub_rn(b.z, b.x), __fsub_rn(b.w, b.y));
  float den = __fadd_rn(__fsub_rn(__fadd_rn(a1, a2), inter), 1e-8f);
  return __fdiv_rn(inter, den);
}

// ---------------------------- anchors (+ counter zeroing) ----------------------

__global__ __launch_bounds__(256) void k_anchors(float4* __restrict__ anchors,
                                                 unsigned int* __restrict__ gcnt,
                                                 unsigned int* __restrict__ oflow) {
  int n = blockIdx.x * 256 + threadIdx.x;
  if (n < NBC) { gcnt[n] = 0u; oflow[n] = 0u; }
  if (n >= NANCH) return;
  int l, off;
  if (n < 36864)      { l = 0; off = 0; }
  else if (n < 46080) { l = 1; off = 36864; }
  else if (n < 48384) { l = 2; off = 46080; }
  else if (n < 48960) { l = 3; off = 48384; }
  else                { l = 4; off = 48960; }
  int stride = 8 << l;
  int feat = 64 >> l;
  int r = n - off;
  int cell = r / 9, a = r - cell * 9;
  int iy = cell / feat, ix = cell - iy * feat;
  int isc = a / 3, ir = a - isc * 3;
  // numpy computes half-sizes in float64, then casts to float32
  double base = exp2((double)isc / 3.0) * (double)stride * 4.0;
  double rt = (ir == 0) ? 1.0 : (ir == 1 ? 0.5 : 2.0);
  double sq = sqrt(rt);
  float hh = (float)(base / sq / 2.0);
  float hw = (float)(base * sq / 2.0);
  float cy = __fmul_rn(__fadd_rn((float)iy, 0.5f), (float)stride);
  float cx = __fmul_rn(__fadd_rn((float)ix, 0.5f), (float)stride);
  anchors[n] = make_float4(__fsub_rn(cy, hh), __fsub_rn(cx, hw),
                           __fadd_rn(cy, hh), __fadd_rn(cx, hw));
}

// ---------------------------- decode -------------------------------------------

__global__ __launch_bounds__(256) void k_decode(const float4* __restrict__ deltas,
                                                const float4* __restrict__ anchors,
                                                float4* __restrict__ boxes) {
  int i = blockIdx.x * 256 + threadIdx.x;
  if (i >= NB * NANCH) return;
  int n = i % NANCH;
  float4 a = anchors[n];
  float4 d = deltas[i];
  float ah = __fsub_rn(a.z, a.x);
  float aw = __fsub_rn(a.w, a.y);
  float acy = __fmul_rn(__fadd_rn(a.x, a.z), 0.5f);
  float acx = __fmul_rn(__fadd_rn(a.y, a.w), 0.5f);
  float cy = __fadd_rn(__fmul_rn(d.x, ah), acy);
  float cx = __fadd_rn(__fmul_rn(d.y, aw), acx);
  float h = __fmul_rn(expf(d.z), ah);
  float w = __fmul_rn(expf(d.w), aw);
  float y1 = __fsub_rn(cy, __fmul_rn(h, 0.5f));
  float x1 = __fsub_rn(cx, __fmul_rn(w, 0.5f));
  float y2 = __fadd_rn(cy, __fmul_rn(h, 0.5f));
  float x2 = __fadd_rn(cx, __fmul_rn(w, 0.5f));
  const float inv = 0.001953125f;  // 1/512, exact
  y1 = fminf(fmaxf(__fmul_rn(y1, inv), 0.0f), 1.0f);
  x1 = fminf(fmaxf(__fmul_rn(x1, inv), 0.0f), 1.0f);
  y2 = fminf(fmaxf(__fmul_rn(y2, inv), 0.0f), 1.0f);
  x2 = fminf(fmaxf(__fmul_rn(x2, inv), 0.0f), 1.0f);
  boxes[i] = make_float4(y1, x1, y2, x2);
}

// ------------- candidate scan: LDS-aggregated, 1 reservation atomic ------------
// grid (NCH, NB). Block = 512 anchors x 90 classes, coalesced float4 stream.
// Candidates collected in per-class LDS lists; ONE global atomicAdd per
// (class,chunk) reserves slots in R2's per-bc gcand list. Order within the list
// is nondeterministic -> canonicalized by t1's sort (proven R2 contract).

__global__ __launch_bounds__(256) void k_scan(const float4* __restrict__ logits4,
                                              unsigned long long* __restrict__ gcand,
                                              unsigned int* __restrict__ gcnt,
                                              unsigned int* __restrict__ oflow) {
  int b = blockIdx.y;
  int ch = blockIdx.x;
  int n0 = ch * CHUNK;
  int rows = min(CHUNK, NANCH - n0);
  const float4* base = logits4 + ((size_t)b * NANCH + n0) * 90 / 4;
  int tot4 = rows * 90 / 4;
  int tid = threadIdx.x;

  __shared__ unsigned long long lc[NC * LCAP];  // 23 KB
  __shared__ unsigned int lcnt[NC];
  for (int c = tid; c < NC; c += 256) lcnt[c] = 0u;
  __syncthreads();

  for (int e4 = tid; e4 < tot4; e4 += 1024) {
    float4 v[4];
#pragma unroll
    for (int k = 0; k < 4; k++) {
      int idx = e4 + k * 256;
      if (idx < tot4) v[k] = base[idx];
    }
#pragma unroll
    for (int k = 0; k < 4; k++) {
      int idx = e4 + k * 256;
      if (idx >= tot4) break;
      float xs[4] = {v[k].x, v[k].y, v[k].z, v[k].w};
#pragma unroll
      for (int j = 0; j < 4; j++) {
        float x = xs[j];
        if (x >= PRECHK) {  // skips sigmoid for ~98% of elements
          float s = sigmoid_ref(x);
          if (s >= EDGE) {
            int e = idx * 4 + j;
            int r = e / 90, c = e - r * 90;
            unsigned int pos = atomicAdd(&lcnt[c], 1u);  // LDS atomic (on-CU)
            if (pos < LCAP) {
              int n = n0 + r;
              lc[c * LCAP + pos] =
                  ((unsigned long long)__float_as_uint(s) << 32) |
                  (unsigned int)(65535 - n);  // u64 desc == score desc, n asc
            }
          }
        }
      }
    }
  }
  __syncthreads();

  // reserve + flush: one global atomic per (class,chunk) with candidates
  if (tid < NC) {
    unsigned int cnt = lcnt[tid];
    int bc = b * NC + tid;
    if (cnt > LCAP) {  // ~1e-16 probability: flag bc for exact fallback
      atomicOr(&oflow[bc], 1u);
      cnt = LCAP;
    }
    if (cnt > 0) {
      unsigned int pos0 = atomicAdd(&gcnt[bc], cnt);
      for (unsigned int k = 0; k < cnt; k++) {
        unsigned int p = pos0 + k;
        if (p < T1CAP) gcand[(size_t)bc * T1CAP + p] = lc[tid * LCAP + k];
      }
    }
  }
}

// -------------------- tier1: sort <=1024 candidates + greedy NMS ----------------
// (verbatim R2-passing kernel + oflow check)

__global__ __launch_bounds__(256) void k_nms_t1(
    const unsigned long long* __restrict__ gcand,
    const unsigned int* __restrict__ gcnt, const unsigned int* __restrict__ oflow,
    const float4* __restrict__ boxes, float* __restrict__ sel_s,
    float4* __restrict__ sel_b, int* __restrict__ flags) {
  int bc = blockIdx.x;
  int b = bc / NC;
  int tid = threadIdx.x;

  __shared__ unsigned long long cand[T1CAP];
  __shared__ float4 cbox[T1CAP];
  __shared__ unsigned char alive[T1CAP];
  __shared__ float4 s_selbox[POSTN];
  __shared__ float s_sels[POSTN];
  __shared__ int s_nsel;

  unsigned int cnt = gcnt[bc];
  bool overflow = (cnt > (unsigned)T1CAP) || (oflow[bc] != 0u);
  int M = (int)min(cnt, (unsigned)T1CAP);
  for (int e = tid; e < T1CAP; e += 256)
    cand[e] = (e < M) ? gcand[(size_t)bc * T1CAP + e] : 0ull;
  if (tid == 0) s_nsel = 0;
  __syncthreads();

  // bitonic sort descending (key = score desc, tie idx asc via 65535-n packing)
  for (int k = 2; k <= T1CAP; k <<= 1) {
    for (int j = k >> 1; j > 0; j >>= 1) {
      for (int t = tid; t < T1CAP / 2; t += 256) {
        int i = ((t & ~(j - 1)) << 1) | (t & (j - 1));
        int p = i | j;
        unsigned long long a = cand[i], bb = cand[p];
        bool up = ((i & k) == 0);
        if (up ? (a < bb) : (a > bb)) { cand[i] = bb; cand[p] = a; }
      }
      __syncthreads();
    }
  }

  for (int e = tid; e < M; e += 256) {
    int n = 65535 - (int)(cand[e] & 0xFFFFull);
    cbox[e] = boxes[(size_t)b * NANCH + n];
    alive[e] = 1;
  }
  __syncthreads();

  // serial greedy NMS (exact reference order: score desc, anchor idx asc)
  for (int i = 0; i < M; i++) {
    if (s_nsel >= POSTN) break;  // uniform (barriered)
    if (!alive[i]) continue;     // uniform
    float4 bi = cbox[i];
    float sc = __uint_as_float((unsigned int)(cand[i] >> 32));
    if (!(iou_ref(bi, bi) > 0.5f)) {
      // degenerate zero-area box: never self-suppresses -> reference re-selects
      // it for every remaining step ("sticky" fill)
      if (tid == 0) {
        for (int p = s_nsel; p < POSTN; p++) { s_selbox[p] = bi; s_sels[p] = sc; }
        s_nsel = POSTN;
      }
      __syncthreads();
      break;
    }
    for (int t = i + 1 + tid; t < M; t += 256)
      if (alive[t] && iou_ref(cbox[t], bi) > 0.5f) alive[t] = 0;
    if (tid == 0) {
      s_selbox[s_nsel] = bi;
      s_sels[s_nsel] = sc;
      s_nsel = s_nsel + 1;
    }
    __syncthreads();
  }
  __syncthreads();
  int ns = s_nsel;

  // valid only if 100 selections completed from a complete (non-overflowed) list
  bool bad = overflow || (ns < POSTN);
  if (tid == 0) flags[bc] = bad ? 1 : 0;
  if (bad) return;
  for (int p = tid; p < POSTN; p += 256) {
    float s0 = s_sels[p];
    bool valid = (s0 > 0.2f);  // SCORE_THR gate (always true here: s0>=EDGE)
    sel_s[bc * POSTN + p] = valid ? s0 : 0.0f;
    sel_b[bc * POSTN + p] = valid ? s_selbox[p] : make_float4(0, 0, 0, 0);
  }
}

// -------- flag-all helper (only if workspace too small for scan buffers) -------

__global__ __launch_bounds__(256) void k_flagall(int* __restrict__ flags) {
  int i = blockIdx.x * 256 + threadIdx.x;
  if (i < NBC) flags[i] = 1;
}

// -------- exact fallback: histogram rank-5000 + sort + NMS (rare/never) --------

template <int CAP, int RANK>
__global__ __launch_bounds__(256) void k_nms_fb(const float* __restrict__ logits,
                                                const float4* __restrict__ boxes,
                                                float* __restrict__ sel_s,
                                                float4* __restrict__ sel_b,
                                                const int* __restrict__ flags) {
  int bc = blockIdx.x;
  if (flags[bc] == 0) return;
  int b = bc / NC;
  int c = bc - b * NC;
  int tid = threadIdx.x;

  __shared__ unsigned int s_key[CAP];
  __shared__ unsigned short s_idx[CAP];
  __shared__ __align__(16) unsigned char s_pool[8192];
  __shared__ unsigned int s_bsum[256];
  __shared__ unsigned char s_alive[512];
  __shared__ float4 s_selbox[POSTN];
  __shared__ float s_sels[POSTN];
  __shared__ int s_cnt, s_nsel, s_cutbin;

  const float* lrow = logits + (size_t)b * NANCH * 90 + c;

  unsigned int* hist = (unsigned int*)s_pool;
  for (int e = tid; e < 2048; e += 256) hist[e] = 0u;
  if (tid == 0) { s_cnt = 0; s_nsel = 0; s_cutbin = 0; }
  __syncthreads();

  for (int n = tid; n < NANCH; n += 256) {
    float s = sigmoid_ref(lrow[(size_t)n * 90]);
    int bin = (int)(s * 2048.0f);
    if (bin > 2047) bin = 2047;
    atomicAdd(&hist[bin], 1u);
  }
  __syncthreads();
  unsigned int loc = 0;
#pragma unroll
  for (int k = 0; k < 8; k++) loc += hist[tid * 8 + k];
  s_bsum[tid] = loc;
  __syncthreads();
  if (tid == 0) {
    unsigned int cum = 0;
    int bin = 0;
    bool fnd = false;
    for (int t = 255; t >= 0 && !fnd; t--) {
      if (cum + s_bsum[t] >= (unsigned)RANK) {
        for (int kk = 7; kk >= 0; kk--) {
          unsigned int h = hist[t * 8 + kk];
          if (cum + h >= (unsigned)RANK) { bin = t * 8 + kk; fnd = true; break; }
          cum += h;
        }
      } else {
        cum += s_bsum[t];
      }
    }
    s_cutbin = bin;
  }
  __syncthreads();
  float edge = __fmul_rn((float)s_cutbin, (1.0f / 2048.0f));  // exact

  for (int n = tid; n < NANCH; n += 256) {
    float s = sigmoid_ref(lrow[(size_t)n * 90]);
    if (s >= edge) {
      int pos = atomicAdd(&s_cnt, 1);
      if (pos < CAP) {
        s_key[pos] = __float_as_uint(s);
        s_idx[pos] = (unsigned short)n;
      }
    }
  }
  __syncthreads();
  int M = s_cnt;
  if (M > CAP) M = CAP;
  for (int e = M + tid; e < CAP; e += 256) { s_key[e] = 0u; s_idx[e] = 0xFFFFu; }
  __syncthreads();

  for (int k = 2; k <= CAP; k <<= 1) {
    for (int j = k >> 1; j > 0; j >>= 1) {
      for (int t = tid; t < CAP / 2; t += 256) {
        int i = ((t & ~(j - 1)) << 1) | (t & (j - 1));
        int p = i | j;
        unsigned int ka = s_key[i], kb = s_key[p];
        unsigned short ia = s_idx[i], ib = s_idx[p];
        bool up = ((i & k) == 0);
        bool g = (ka < kb) || (ka == kb && ia > ib);
        bool l = (kb < ka) || (ka == kb && ib > ia);
        if (up ? g : l) {
          s_key[i] = kb; s_key[p] = ka;
          s_idx[i] = ib; s_idx[p] = ia;
        }
      }
      __syncthreads();
    }
  }

  float4* cbox = (float4*)s_pool;
  int L = (M < 5000) ? M : 5000;  // PRE_NMS truncation (stable)
  for (int base = 0; base < L; base += 512) {
    int cn = min(512, L - base);
    int ns0 = s_nsel;
    if (ns0 >= POSTN) break;
    for (int t = tid; t < cn; t += 256) {
      int n = s_idx[base + t];
      float4 bx = boxes[(size_t)b * NANCH + n];
      bool al = true;
      for (int s = 0; s < ns0; s++) {
        if (iou_ref(bx, s_selbox[s]) > 0.5f) { al = false; break; }
      }
      cbox[t] = bx;
      s_alive[t] = al ? 1 : 0;
    }
    __syncthreads();
    for (int i = 0; i < cn; i++) {
      if (s_nsel >= POSTN) break;
      if (!s_alive[i]) continue;
      float4 bi = cbox[i];
      float sc = __uint_as_float(s_key[base + i]);
      if (!(iou_ref(bi, bi) > 0.5f)) {
        if (tid == 0) {
          for (int p = s_nsel; p < POSTN; p++) { s_selbox[p] = bi; s_sels[p] = sc; }
          s_nsel = POSTN;
        }
        __syncthreads();
        break;
      }
      for (int t = tid; t < cn; t += 256) {
        if (t > i && s_alive[t] && iou_ref(cbox[t], bi) > 0.5f) s_alive[t] = 0;
      }
      if (tid == 0) {
        s_selbox[s_nsel] = bi;
        s_sels[s_nsel] = sc;
        s_nsel = s_nsel + 1;
      }
      __syncthreads();
    }
    __syncthreads();
    if (s_nsel >= POSTN) break;
  }
  __syncthreads();
  int ns = s_nsel;
  for (int p = tid; p < POSTN; p += 256) {
    float sc = 0.0f;
    float4 bx = make_float4(0.0f, 0.0f, 0.0f, 0.0f);
    if (p < ns) {
      float s0 = s_sels[p];
      if (s0 > 0.2f) { sc = s0; bx = s_selbox[p]; }
    }
    sel_s[bc * POSTN + p] = sc;
    sel_b[bc * POSTN + p] = bx;
  }
}

// ---------------- per-batch top-100: frontier merge (verbatim R2) ---------------
// Per-class sel_s rows are non-increasing. Stable top-100 == 100 steps of a
// stable 90-way frontier max.

__global__ __launch_bounds__(256) void k_final(const float* __restrict__ sel_s,
                                               const float4* __restrict__ sel_b,
                                               float* __restrict__ out) {
  int b = blockIdx.x;
  int tid = threadIdx.x;
  __shared__ float key[9000];
  __shared__ int ptr[NC];
  __shared__ unsigned long long wred[4];
  __shared__ unsigned int win_k[POSTN];
  __shared__ int win_e[POSTN];
  for (int e = tid; e < 9000; e += 256) key[e] = sel_s[(size_t)b * 9000 + e];
  if (tid < NC) ptr[tid] = 0;
  __syncthreads();
  int lane = tid & 63, wid = tid >> 6;
  for (int p = 0; p < POSTN; p++) {
    unsigned long long v = 0ull;
    if (tid < NC) {
      int pp = ptr[tid];
      if (pp < POSTN) {
        int e = tid * POSTN + pp;
        v = ((unsigned long long)__float_as_uint(key[e]) << 32) |
            (unsigned int)(16383 - e);  // max score, then min flat idx (stable)
      }
    }
    for (int d = 32; d > 0; d >>= 1) {
      unsigned long long o = __shfl_down(v, (unsigned)d, 64);
      if (o > v) v = o;
    }
    if (lane == 0) wred[wid] = v;
    __syncthreads();
    if (tid == 0) {
      unsigned long long w = wred[0];
      if (wred[1] > w) w = wred[1];
      int e = 16383 - (int)(w & 0x3FFFull);
      win_k[p] = (unsigned int)(w >> 32);
      win_e[p] = e;
      ptr[e / POSTN] = (e % POSTN) + 1;
    }
    __syncthreads();
  }
  if (tid < POSTN) {
    int p = tid;
    unsigned int k = win_k[p];
    int e = win_e[p];
    float4 bx = sel_b[(size_t)b * 9000 + e];
    ((float4*)out)[b * POSTN + p] = bx;              // out_b [8,100,4]
    out[3200 + b * POSTN + p] = __uint_as_float(k);  // out_s [8,100]
    out[4000 + b * POSTN + p] = (float)(e / POSTN);  // out_c [8,100]
  }
  if (tid == 0) {
    int v = 0;
    for (int p = 0; p < POSTN; p++) v += (win_k[p] != 0u) ? 1 : 0;
    out[4800 + b] = (float)v;  // valid [8]
  }
}

// ------------------------------- launcher --------------------------------------

extern "C" void kernel_launch(void* const* d_in, const int* in_sizes, int n_in,
                              void* d_out, int out_size, void* d_ws, size_t ws_size,
                              hipStream_t stream) {
  const float* deltas = (const float*)d_in[0];  // [8,49104,4]
  const float* logits = (const float*)d_in[1];  // [8,49104,90]
  float* out = (float*)d_out;
  char* ws = (char*)d_ws;

  size_t off = 0;
  auto take = [&](size_t bytes) -> char* {
    char* p = ws + off;
    off += (bytes + 255) & ~(size_t)255;
    return p;
  };
  // small/required buffers first so the degraded path fits in ~8.6 MB
  float4* anchors = (float4*)take((size_t)NANCH * 16);
  float4* boxes = (float4*)take((size_t)NB * NANCH * 16);
  float* sel_s = (float*)take((size_t)NBC * POSTN * 4);
  float4* sel_b = (float4*)take((size_t)NBC * POSTN * 16);
  int* flags = (int*)take((size_t)NBC * 4);
  unsigned int* gcnt = (unsigned int*)take((size_t)NBC * 4);
  unsigned int* oflow = (unsigned int*)take((size_t)NBC * 4);
  unsigned long long* gcand =
      (unsigned long long*)take((size_t)NBC * T1CAP * 8);
  bool fits = (off <= ws_size);  // total ~14.42 MB (R2-proven budget + 3 KB)

  k_anchors<<<dim3((NANCH + 255) / 256), dim3(256), 0, stream>>>(anchors, gcnt,
                                                                 oflow);
  k_decode<<<dim3((NB * NANCH + 255) / 256), dim3(256), 0, stream>>>(
      (const float4*)deltas, anchors, boxes);
  if (fits) {
    k_scan<<<dim3(NCH, NB), dim3(256), 0, stream>>>((const float4*)logits,
                                                    gcand, gcnt, oflow);
    k_nms_t1<<<dim3(NBC), dim3(256), 0, stream>>>(gcand, gcnt, oflow, boxes,
                                                  sel_s, sel_b, flags);
  } else {
    k_flagall<<<dim3((NBC + 255) / 256), dim3(256), 0, stream>>>(flags);
  }
  k_nms_fb<8192, 5000><<<dim3(NBC), dim3(256), 0, stream>>>(logits, boxes,
                                                            sel_s, sel_b, flags);
  k_final<<<dim3(NB), dim3(256), 0, stream>>>(sel_s, sel_b, out);
}

// Round 6
// 369.797 us; speedup vs baseline: 1.8679x; 1.0475x over previous
//
#include <hip/hip_runtime.h>
#include <math.h>

// EfficientDet postprocess for MI355X — round 6.
// R4-proven pipeline verbatim; ONLY change: k_nms_t1 runs at 512 threads
// (mechanical stride 256->512) to halve sort/sweep iteration counts.
// R5's t1 rewrite (preselect+matrix NMS) failed and is abandoned pending
// understanding; this round is the safe recovery + measured speedup.

#define NANCH 49104
#define NB 8
#define NC 90
#define NBC 720
#define POSTN 100
#define T1CAP 1024
#define CHUNK 512
#define NCH 96          // ceil(49104/512)
#define LCAP 32         // per-(class,chunk) LDS list cap; Poisson(5.3) -> ~11 sigma
#define EDGE 0.91f      // P(sigmoid(N(0,1)) >= 0.91) ~ 1.04% -> ~509 +/- 22 per (b,c)
#define PRECHK 2.0f     // sigmoid(2.0)=0.8808 < EDGE: safe cheap pre-filter

// ---------- exact-float helpers (mirror numpy f32 semantics, no FMA) ----------

__device__ __forceinline__ float sigmoid_ref(float x) {
  if (x >= 0.0f) return __fdiv_rn(1.0f, __fadd_rn(1.0f, expf(-x)));
  float e = expf(x);
  return __fdiv_rn(e, __fadd_rn(1.0f, e));
}

__device__ __forceinline__ float iou_ref(float4 a, float4 b) {
  float yy1 = fmaxf(a.x, b.x);
  float xx1 = fmaxf(a.y, b.y);
  float yy2 = fminf(a.z, b.z);
  float xx2 = fminf(a.w, b.w);
  float ih = fmaxf(__fsub_rn(yy2, yy1), 0.0f);
  float iw = fmaxf(__fsub_rn(xx2, xx1), 0.0f);
  float inter = __fmul_rn(ih, iw);
  float a1 = __fmul_rn(__fsub_rn(a.z, a.x), __fsub_rn(a.w, a.y));
  float a2 = __fmul_rn(__fsub_rn(b.z, b.x), __fsub_rn(b.w, b.y));
  float den = __fadd_rn(__fsub_rn(__fadd_rn(a1, a2), inter), 1e-8f);
  return __fdiv_rn(inter, den);
}

// ---------------------------- anchors (+ counter zeroing) ----------------------

__global__ __launch_bounds__(256) void k_anchors(float4* __restrict__ anchors,
                                                 unsigned int* __restrict__ gcnt,
                                                 unsigned int* __restrict__ oflow) {
  int n = blockIdx.x * 256 + threadIdx.x;
  if (n < NBC) { gcnt[n] = 0u; oflow[n] = 0u; }
  if (n >= NANCH) return;
  int l, off;
  if (n < 36864)      { l = 0; off = 0; }
  else if (n < 46080) { l = 1; off = 36864; }
  else if (n < 48384) { l = 2; off = 46080; }
  else if (n < 48960) { l = 3; off = 48384; }
  else                { l = 4; off = 48960; }
  int stride = 8 << l;
  int feat = 64 >> l;
  int r = n - off;
  int cell = r / 9, a = r - cell * 9;
  int iy = cell / feat, ix = cell - iy * feat;
  int isc = a / 3, ir = a - isc * 3;
  // numpy computes half-sizes in float64, then casts to float32
  double base = exp2((double)isc / 3.0) * (double)stride * 4.0;
  double rt = (ir == 0) ? 1.0 : (ir == 1 ? 0.5 : 2.0);
  double sq = sqrt(rt);
  float hh = (float)(base / sq / 2.0);
  float hw = (float)(base * sq / 2.0);
  float cy = __fmul_rn(__fadd_rn((float)iy, 0.5f), (float)stride);
  float cx = __fmul_rn(__fadd_rn((float)ix, 0.5f), (float)stride);
  anchors[n] = make_float4(__fsub_rn(cy, hh), __fsub_rn(cx, hw),
                           __fadd_rn(cy, hh), __fadd_rn(cx, hw));
}

// ---------------------------- decode -------------------------------------------

__global__ __launch_bounds__(256) void k_decode(const float4* __restrict__ deltas,
                                                const float4* __restrict__ anchors,
                                                float4* __restrict__ boxes) {
  int i = blockIdx.x * 256 + threadIdx.x;
  if (i >= NB * NANCH) return;
  int n = i % NANCH;
  float4 a = anchors[n];
  float4 d = deltas[i];
  float ah = __fsub_rn(a.z, a.x);
  float aw = __fsub_rn(a.w, a.y);
  float acy = __fmul_rn(__fadd_rn(a.x, a.z), 0.5f);
  float acx = __fmul_rn(__fadd_rn(a.y, a.w), 0.5f);
  float cy = __fadd_rn(__fmul_rn(d.x, ah), acy);
  float cx = __fadd_rn(__fmul_rn(d.y, aw), acx);
  float h = __fmul_rn(expf(d.z), ah);
  float w = __fmul_rn(expf(d.w), aw);
  float y1 = __fsub_rn(cy, __fmul_rn(h, 0.5f));
  float x1 = __fsub_rn(cx, __fmul_rn(w, 0.5f));
  float y2 = __fadd_rn(cy, __fmul_rn(h, 0.5f));
  float x2 = __fadd_rn(cx, __fmul_rn(w, 0.5f));
  const float inv = 0.001953125f;  // 1/512, exact
  y1 = fminf(fmaxf(__fmul_rn(y1, inv), 0.0f), 1.0f);
  x1 = fminf(fmaxf(__fmul_rn(x1, inv), 0.0f), 1.0f);
  y2 = fminf(fmaxf(__fmul_rn(y2, inv), 0.0f), 1.0f);
  x2 = fminf(fmaxf(__fmul_rn(x2, inv), 0.0f), 1.0f);
  boxes[i] = make_float4(y1, x1, y2, x2);
}

// ------------- candidate scan: LDS-aggregated, 1 reservation atomic ------------
// (verbatim R4-passing kernel)

__global__ __launch_bounds__(256) void k_scan(const float4* __restrict__ logits4,
                                              unsigned long long* __restrict__ gcand,
                                              unsigned int* __restrict__ gcnt,
                                              unsigned int* __restrict__ oflow) {
  int b = blockIdx.y;
  int ch = blockIdx.x;
  int n0 = ch * CHUNK;
  int rows = min(CHUNK, NANCH - n0);
  const float4* base = logits4 + ((size_t)b * NANCH + n0) * 90 / 4;
  int tot4 = rows * 90 / 4;
  int tid = threadIdx.x;

  __shared__ unsigned long long lc[NC * LCAP];  // 23 KB
  __shared__ unsigned int lcnt[NC];
  for (int c = tid; c < NC; c += 256) lcnt[c] = 0u;
  __syncthreads();

  for (int e4 = tid; e4 < tot4; e4 += 1024) {
    float4 v[4];
#pragma unroll
    for (int k = 0; k < 4; k++) {
      int idx = e4 + k * 256;
      if (idx < tot4) v[k] = base[idx];
    }
#pragma unroll
    for (int k = 0; k < 4; k++) {
      int idx = e4 + k * 256;
      if (idx >= tot4) break;
      float xs[4] = {v[k].x, v[k].y, v[k].z, v[k].w};
#pragma unroll
      for (int j = 0; j < 4; j++) {
        float x = xs[j];
        if (x >= PRECHK) {  // skips sigmoid for ~98% of elements
          float s = sigmoid_ref(x);
          if (s >= EDGE) {
            int e = idx * 4 + j;
            int r = e / 90, c = e - r * 90;
            unsigned int pos = atomicAdd(&lcnt[c], 1u);  // LDS atomic (on-CU)
            if (pos < LCAP) {
              int n = n0 + r;
              lc[c * LCAP + pos] =
                  ((unsigned long long)__float_as_uint(s) << 32) |
                  (unsigned int)(65535 - n);  // u64 desc == score desc, n asc
            }
          }
        }
      }
    }
  }
  __syncthreads();

  // reserve + flush: one global atomic per (class,chunk) with candidates
  if (tid < NC) {
    unsigned int cnt = lcnt[tid];
    int bc = b * NC + tid;
    if (cnt > LCAP) {  // ~1e-16 probability: flag bc for exact fallback
      atomicOr(&oflow[bc], 1u);
      cnt = LCAP;
    }
    if (cnt > 0) {
      unsigned int pos0 = atomicAdd(&gcnt[bc], cnt);
      for (unsigned int k = 0; k < cnt; k++) {
        unsigned int p = pos0 + k;
        if (p < T1CAP) gcand[(size_t)bc * T1CAP + p] = lc[tid * LCAP + k];
      }
    }
  }
}

// -------------------- tier1: sort <=1024 candidates + greedy NMS ----------------
// R4-proven algorithm, mechanically widened to 512 threads (stride 256->512):
// sort = 1 pair/thread/stage, suppression sweep = 1 iteration over M.

__global__ __launch_bounds__(512) void k_nms_t1(
    const unsigned long long* __restrict__ gcand,
    const unsigned int* __restrict__ gcnt, const unsigned int* __restrict__ oflow,
    const float4* __restrict__ boxes, float* __restrict__ sel_s,
    float4* __restrict__ sel_b, int* __restrict__ flags) {
  int bc = blockIdx.x;
  int b = bc / NC;
  int tid = threadIdx.x;

  __shared__ unsigned long long cand[T1CAP];
  __shared__ float4 cbox[T1CAP];
  __shared__ unsigned char alive[T1CAP];
  __shared__ float4 s_selbox[POSTN];
  __shared__ float s_sels[POSTN];
  __shared__ int s_nsel;

  unsigned int cnt = gcnt[bc];
  bool overflow = (cnt > (unsigned)T1CAP) || (oflow[bc] != 0u);
  int M = (int)min(cnt, (unsigned)T1CAP);
  for (int e = tid; e < T1CAP; e += 512)
    cand[e] = (e < M) ? gcand[(size_t)bc * T1CAP + e] : 0ull;
  if (tid == 0) s_nsel = 0;
  __syncthreads();

  // bitonic sort descending (key = score desc, tie idx asc via 65535-n packing)
  for (int k = 2; k <= T1CAP; k <<= 1) {
    for (int j = k >> 1; j > 0; j >>= 1) {
      int t = tid;  // T1CAP/2 == 512 pairs == blockDim
      int i = ((t & ~(j - 1)) << 1) | (t & (j - 1));
      int p = i | j;
      unsigned long long a = cand[i], bb = cand[p];
      bool up = ((i & k) == 0);
      if (up ? (a < bb) : (a > bb)) { cand[i] = bb; cand[p] = a; }
      __syncthreads();
    }
  }

  for (int e = tid; e < M; e += 512) {
    int n = 65535 - (int)(cand[e] & 0xFFFFull);
    cbox[e] = boxes[(size_t)b * NANCH + n];
    alive[e] = 1;
  }
  __syncthreads();

  // serial greedy NMS (exact reference order: score desc, anchor idx asc)
  for (int i = 0; i < M; i++) {
    if (s_nsel >= POSTN) break;  // uniform (barriered)
    if (!alive[i]) continue;     // uniform
    float4 bi = cbox[i];
    float sc = __uint_as_float((unsigned int)(cand[i] >> 32));
    if (!(iou_ref(bi, bi) > 0.5f)) {
      // degenerate zero-area box: never self-suppresses -> reference re-selects
      // it for every remaining step ("sticky" fill)
      if (tid == 0) {
        for (int p = s_nsel; p < POSTN; p++) { s_selbox[p] = bi; s_sels[p] = sc; }
        s_nsel = POSTN;
      }
      __syncthreads();
      break;
    }
    for (int t = i + 1 + tid; t < M; t += 512)
      if (alive[t] && iou_ref(cbox[t], bi) > 0.5f) alive[t] = 0;
    if (tid == 0) {
      s_selbox[s_nsel] = bi;
      s_sels[s_nsel] = sc;
      s_nsel = s_nsel + 1;
    }
    __syncthreads();
  }
  __syncthreads();
  int ns = s_nsel;

  // valid only if 100 selections completed from a complete (non-overflowed) list
  bool bad = overflow || (ns < POSTN);
  if (tid == 0) flags[bc] = bad ? 1 : 0;
  if (bad) return;
  for (int p = tid; p < POSTN; p += 512) {
    float s0 = s_sels[p];
    bool valid = (s0 > 0.2f);  // SCORE_THR gate (always true here: s0>=EDGE)
    sel_s[bc * POSTN + p] = valid ? s0 : 0.0f;
    sel_b[bc * POSTN + p] = valid ? s_selbox[p] : make_float4(0, 0, 0, 0);
  }
}

// -------- flag-all helper (only if workspace too small for scan buffers) -------

__global__ __launch_bounds__(256) void k_flagall(int* __restrict__ flags) {
  int i = blockIdx.x * 256 + threadIdx.x;
  if (i < NBC) flags[i] = 1;
}

// -------- exact fallback: histogram rank-5000 + sort + NMS (rare/never) --------

template <int CAP, int RANK>
__global__ __launch_bounds__(256) void k_nms_fb(const float* __restrict__ logits,
                                                const float4* __restrict__ boxes,
                                                float* __restrict__ sel_s,
                                                float4* __restrict__ sel_b,
                                                const int* __restrict__ flags) {
  int bc = blockIdx.x;
  if (flags[bc] == 0) return;
  int b = bc / NC;
  int c = bc - b * NC;
  int tid = threadIdx.x;

  __shared__ unsigned int s_key[CAP];
  __shared__ unsigned short s_idx[CAP];
  __shared__ __align__(16) unsigned char s_pool[8192];
  __shared__ unsigned int s_bsum[256];
  __shared__ unsigned char s_alive[512];
  __shared__ float4 s_selbox[POSTN];
  __shared__ float s_sels[POSTN];
  __shared__ int s_cnt, s_nsel, s_cutbin;

  const float* lrow = logits + (size_t)b * NANCH * 90 + c;

  unsigned int* hist = (unsigned int*)s_pool;
  for (int e = tid; e < 2048; e += 256) hist[e] = 0u;
  if (tid == 0) { s_cnt = 0; s_nsel = 0; s_cutbin = 0; }
  __syncthreads();

  for (int n = tid; n < NANCH; n += 256) {
    float s = sigmoid_ref(lrow[(size_t)n * 90]);
    int bin = (int)(s * 2048.0f);
    if (bin > 2047) bin = 2047;
    atomicAdd(&hist[bin], 1u);
  }
  __syncthreads();
  unsigned int loc = 0;
#pragma unroll
  for (int k = 0; k < 8; k++) loc += hist[tid * 8 + k];
  s_bsum[tid] = loc;
  __syncthreads();
  if (tid == 0) {
    unsigned int cum = 0;
    int bin = 0;
    bool fnd = false;
    for (int t = 255; t >= 0 && !fnd; t--) {
      if (cum + s_bsum[t] >= (unsigned)RANK) {
        for (int kk = 7; kk >= 0; kk--) {
          unsigned int h = hist[t * 8 + kk];
          if (cum + h >= (unsigned)RANK) { bin = t * 8 + kk; fnd = true; break; }
          cum += h;
        }
      } else {
        cum += s_bsum[t];
      }
    }
    s_cutbin = bin;
  }
  __syncthreads();
  float edge = __fmul_rn((float)s_cutbin, (1.0f / 2048.0f));  // exact

  for (int n = tid; n < NANCH; n += 256) {
    float s = sigmoid_ref(lrow[(size_t)n * 90]);
    if (s >= edge) {
      int pos = atomicAdd(&s_cnt, 1);
      if (pos < CAP) {
        s_key[pos] = __float_as_uint(s);
        s_idx[pos] = (unsigned short)n;
      }
    }
  }
  __syncthreads();
  int M = s_cnt;
  if (M > CAP) M = CAP;
  for (int e = M + tid; e < CAP; e += 256) { s_key[e] = 0u; s_idx[e] = 0xFFFFu; }
  __syncthreads();

  for (int k = 2; k <= CAP; k <<= 1) {
    for (int j = k >> 1; j > 0; j >>= 1) {
      for (int t = tid; t < CAP / 2; t += 256) {
        int i = ((t & ~(j - 1)) << 1) | (t & (j - 1));
        int p = i | j;
        unsigned int ka = s_key[i], kb = s_key[p];
        unsigned short ia = s_idx[i], ib = s_idx[p];
        bool up = ((i & k) == 0);
        bool g = (ka < kb) || (ka == kb && ia > ib);
        bool l = (kb < ka) || (ka == kb && ib > ia);
        if (up ? g : l) {
          s_key[i] = kb; s_key[p] = ka;
          s_idx[i] = ib; s_idx[p] = ia;
        }
      }
      __syncthreads();
    }
  }

  float4* cbox = (float4*)s_pool;
  int L = (M < 5000) ? M : 5000;  // PRE_NMS truncation (stable)
  for (int base = 0; base < L; base += 512) {
    int cn = min(512, L - base);
    int ns0 = s_nsel;
    if (ns0 >= POSTN) break;
    for (int t = tid; t < cn; t += 256) {
      int n = s_idx[base + t];
      float4 bx = boxes[(size_t)b * NANCH + n];
      bool al = true;
      for (int s = 0; s < ns0; s++) {
        if (iou_ref(bx, s_selbox[s]) > 0.5f) { al = false; break; }
      }
      cbox[t] = bx;
      s_alive[t] = al ? 1 : 0;
    }
    __syncthreads();
    for (int i = 0; i < cn; i++) {
      if (s_nsel >= POSTN) break;
      if (!s_alive[i]) continue;
      float4 bi = cbox[i];
      float sc = __uint_as_float(s_key[base + i]);
      if (!(iou_ref(bi, bi) > 0.5f)) {
        if (tid == 0) {
          for (int p = s_nsel; p < POSTN; p++) { s_selbox[p] = bi; s_sels[p] = sc; }
          s_nsel = POSTN;
        }
        __syncthreads();
        break;
      }
      for (int t = tid; t < cn; t += 256) {
        if (t > i && s_alive[t] && iou_ref(cbox[t], bi) > 0.5f) s_alive[t] = 0;
      }
      if (tid == 0) {
        s_selbox[s_nsel] = bi;
        s_sels[s_nsel] = sc;
        s_nsel = s_nsel + 1;
      }
      __syncthreads();
    }
    __syncthreads();
    if (s_nsel >= POSTN) break;
  }
  __syncthreads();
  int ns = s_nsel;
  for (int p = tid; p < POSTN; p += 256) {
    float sc = 0.0f;
    float4 bx = make_float4(0.0f, 0.0f, 0.0f, 0.0f);
    if (p < ns) {
      float s0 = s_sels[p];
      if (s0 > 0.2f) { sc = s0; bx = s_selbox[p]; }
    }
    sel_s[bc * POSTN + p] = sc;
    sel_b[bc * POSTN + p] = bx;
  }
}

// ---------------- per-batch top-100: frontier merge (verbatim R4) ---------------
// Per-class sel_s rows are non-increasing. Stable top-100 == 100 steps of a
// stable 90-way frontier max.

__global__ __launch_bounds__(256) void k_final(const float* __restrict__ sel_s,
                                               const float4* __restrict__ sel_b,
                                               float* __restrict__ out) {
  int b = blockIdx.x;
  int tid = threadIdx.x;
  __shared__ float key[9000];
  __shared__ int ptr[NC];
  __shared__ unsigned long long wred[4];
  __shared__ unsigned int win_k[POSTN];
  __shared__ int win_e[POSTN];
  for (int e = tid; e < 9000; e += 256) key[e] = sel_s[(size_t)b * 9000 + e];
  if (tid < NC) ptr[tid] = 0;
  __syncthreads();
  int lane = tid & 63, wid = tid >> 6;
  for (int p = 0; p < POSTN; p++) {
    unsigned long long v = 0ull;
    if (tid < NC) {
      int pp = ptr[tid];
      if (pp < POSTN) {
        int e = tid * POSTN + pp;
        v = ((unsigned long long)__float_as_uint(key[e]) << 32) |
            (unsigned int)(16383 - e);  // max score, then min flat idx (stable)
      }
    }
    for (int d = 32; d > 0; d >>= 1) {
      unsigned long long o = __shfl_down(v, (unsigned)d, 64);
      if (o > v) v = o;
    }
    if (lane == 0) wred[wid] = v;
    __syncthreads();
    if (tid == 0) {
      unsigned long long w = wred[0];
      if (wred[1] > w) w = wred[1];
      int e = 16383 - (int)(w & 0x3FFFull);
      win_k[p] = (unsigned int)(w >> 32);
      win_e[p] = e;
      ptr[e / POSTN] = (e % POSTN) + 1;
    }
    __syncthreads();
  }
  if (tid < POSTN) {
    int p = tid;
    unsigned int k = win_k[p];
    int e = win_e[p];
    float4 bx = sel_b[(size_t)b * 9000 + e];
    ((float4*)out)[b * POSTN + p] = bx;              // out_b [8,100,4]
    out[3200 + b * POSTN + p] = __uint_as_float(k);  // out_s [8,100]
    out[4000 + b * POSTN + p] = (float)(e / POSTN);  // out_c [8,100]
  }
  if (tid == 0) {
    int v = 0;
    for (int p = 0; p < POSTN; p++) v += (win_k[p] != 0u) ? 1 : 0;
    out[4800 + b] = (float)v;  // valid [8]
  }
}

// ------------------------------- launcher --------------------------------------

extern "C" void kernel_launch(void* const* d_in, const int* in_sizes, int n_in,
                              void* d_out, int out_size, void* d_ws, size_t ws_size,
                              hipStream_t stream) {
  const float* deltas = (const float*)d_in[0];  // [8,49104,4]
  const float* logits = (const float*)d_in[1];  // [8,49104,90]
  float* out = (float*)d_out;
  char* ws = (char*)d_ws;

  size_t off = 0;
  auto take = [&](size_t bytes) -> char* {
    char* p = ws + off;
    off += (bytes + 255) & ~(size_t)255;
    return p;
  };
  // small/required buffers first so the degraded path fits in ~8.6 MB
  float4* anchors = (float4*)take((size_t)NANCH * 16);
  float4* boxes = (float4*)take((size_t)NB * NANCH * 16);
  float* sel_s = (float*)take((size_t)NBC * POSTN * 4);
  float4* sel_b = (float4*)take((size_t)NBC * POSTN * 16);
  int* flags = (int*)take((size_t)NBC * 4);
  unsigned int* gcnt = (unsigned int*)take((size_t)NBC * 4);
  unsigned int* oflow = (unsigned int*)take((size_t)NBC * 4);
  unsigned long long* gcand =
      (unsigned long long*)take((size_t)NBC * T1CAP * 8);
  bool fits = (off <= ws_size);  // total ~14.42 MB (R4-proven budget)

  k_anchors<<<dim3((NANCH + 255) / 256), dim3(256), 0, stream>>>(anchors, gcnt,
                                                                 oflow);
  k_decode<<<dim3((NB * NANCH + 255) / 256), dim3(256), 0, stream>>>(
      (const float4*)deltas, anchors, boxes);
  if (fits) {
    k_scan<<<dim3(NCH, NB), dim3(256), 0, stream>>>((const float4*)logits,
                                                    gcand, gcnt, oflow);
    k_nms_t1<<<dim3(NBC), dim3(512), 0, stream>>>(gcand, gcnt, oflow, boxes,
                                                  sel_s, sel_b, flags);
  } else {
    k_flagall<<<dim3((NBC + 255) / 256), dim3(256), 0, stream>>>(flags);
  }
  k_nms_fb<8192, 5000><<<dim3(NBC), dim3(256), 0, stream>>>(logits, boxes,
                                                            sel_s, sel_b, flags);
  k_final<<<dim3(NB), dim3(256), 0, stream>>>(sel_s, sel_b, out);
}